// Round 19
// baseline (1959.300 us; speedup 1.0000x reference)
//
#include <hip/hip_runtime.h>
#include <hip/hip_bf16.h>

typedef unsigned short ushortT;
typedef __attribute__((ext_vector_type(8))) short bf16x8;
typedef __attribute__((ext_vector_type(4))) float f32x4;
typedef __attribute__((ext_vector_type(4))) int i32x4;

#define B_SZ 64
#define T_SZ 512
#define D_SZ 256
#define U_SZ 512
#define M_SZ 64

// ---------- helpers ----------
__device__ __forceinline__ ushortT f2b(float f) {
    __hip_bfloat16 h = __float2bfloat16(f);
    union { __hip_bfloat16 h; ushortT u; } c; c.h = h; return c.u;
}
__device__ __forceinline__ float clip10(float v) {
    return fminf(fmaxf(v, -10.f), 10.f);
}
__device__ __forceinline__ float tanh_fast(float z) {
    float e = __expf(2.f * z);
    return 1.f - 2.f / (e + 1.f);   // inf-safe
}
__device__ __forceinline__ float sigm_fast(float z) {
    return 1.f / (1.f + __expf(-z));
}

// ---------- prep: x -> clipped bf16 ----------
__global__ void prep_xb_k(const float* __restrict__ x, ushortT* __restrict__ xb) {
    const int n4 = (B_SZ * T_SZ * D_SZ) / 4;
    for (int i = blockIdx.x * blockDim.x + threadIdx.x; i < n4; i += gridDim.x * blockDim.x) {
        float4 v = ((const float4*)x)[i];
        ushort4 o;
        o.x = f2b(clip10(v.x));
        o.y = f2b(clip10(v.y));
        o.z = f2b(clip10(v.z));
        o.w = f2b(clip10(v.w));
        ((ushort4*)xb)[i] = o;
    }
}

// ---------- prep: U^T and W^T bf16 (transposed, col-major rows) ----------
// UslT cols: 0..2047 gate U cols, 2048..2111 Ue cols.
// WslT cols: 0..2047 gate W cols, 2048..2111 We cols, 2112..2623 Wm cols.
__global__ void prep_uw_k(const float* __restrict__ Ui, const float* __restrict__ Uf,
                          const float* __restrict__ Uo, const float* __restrict__ Uc,
                          const float* __restrict__ Ue,
                          const float* __restrict__ Wi, const float* __restrict__ Wf,
                          const float* __restrict__ Wo, const float* __restrict__ Wc,
                          const float* __restrict__ We, const float* __restrict__ Wm,
                          ushortT* __restrict__ UslT, ushortT* __restrict__ WslT) {
    const int NU = 2112 * 512;
    const int NW = 2624 * 256;
    for (int i = blockIdx.x * blockDim.x + threadIdx.x; i < NU + NW; i += gridDim.x * blockDim.x) {
        if (i < NU) {
            int c = i >> 9, k = i & 511;
            float v;
            if (c < 2048) {
                int g = c >> 9, u = c & 511;
                const float* U = (g == 0) ? Ui : (g == 1) ? Uf : (g == 2) ? Uo : Uc;
                v = U[k * 512 + u];
            } else {
                v = Ue[k * 64 + (c - 2048)];
            }
            UslT[i] = f2b(v);
        } else {
            int j = i - NU;
            int c = j >> 8, k = j & 255;
            float v;
            if (c < 2048) {
                int g = c >> 9, u = c & 511;
                const float* W = (g == 0) ? Wi : (g == 1) ? Wf : (g == 2) ? Wo : Wc;
                v = W[k * 512 + u];
            } else if (c < 2112) {
                v = We[k * 64 + (c - 2048)];
            } else {
                v = Wm[k * 512 + (c - 2112)];
            }
            WslT[j] = f2b(v);
        }
    }
}

#define MEMF_ROW 68
#define MEMF_PB (32 * 68 + 8)   // 2184 floats per batch block

// ---------- persistent recurrent kernel ----------
// R19 = R15 (proven 1649us: speculative mirror read + alternating LLC/mirror
// retry + dual tagged store) restructured to 16 groups x 16 WGs:
//   grp = bid&15 (4 batches/group), rank = bid>>4 (32 units/WG).
// Halves validate fan-in (16 producers) and tile size (128 lines/group).
// Receive path COOPERATIVE (32B/lane). Counted-vmcnt rule respected: only
// NEWER LOADS are ever left outstanding (loads retire in order; stores always
// in the drained set). LLC copy guarantees progress under any placement (G16).
__global__ __launch_bounds__(256, 1) void xlstm_rec(
    const ushortT* __restrict__ xb,    // [B*T][256] bf16 (clipped)
    const ushortT* __restrict__ UslT,  // [2112][512] bf16
    const ushortT* __restrict__ WslT,  // [2624][256] bf16
    const float* __restrict__ bi_p, const float* __restrict__ bf_p,
    const float* __restrict__ bo_p, const float* __restrict__ bc_p,
    const float* __restrict__ be_p,
    unsigned* __restrict__ Hbuf32,     // [2][64][512] u32 tagged h (LLC copy)
    unsigned* __restrict__ Hmir,       // [2][64][512] u32 tagged h (L2 mirror)
    float* __restrict__ out)           // [64][512][512] fp32
{
    const int bid = blockIdx.x, tid = threadIdx.x;
    const int grp = bid & 15, rank = bid >> 4;
    const int wave = tid >> 6, lane = tid & 63;
    const int b0 = grp << 2;     // batch base (4 per group)
    const int u0 = rank << 5;    // unit base (32 per WG)

    __shared__ float memF[4 * MEMF_PB];     // c ring: [pb][pu][slot(64)+pad]
    __shared__ float g_lds[4][4][32];       // i,f,o,ctilde [gate][batch][unit]
    __shared__ float e_lds[4][68];          // raw clipped e-logits
    __shared__ float w_lds[4][72];          // softmax numerators (physical slot)
    __shared__ float zm_lds[4][32];         // x_t @ Wm slice
    __shared__ ushortT hLb[4][520];         // h tile bf16 (4 batch rows)

    for (int i = tid; i < 4 * MEMF_PB; i += 256) memF[i] = 0.f;

    // ---- register-resident weight B-fragments (3 fragments per wave) ----
    // fragment f = wave*3+nt covers cols j = f*16 + (lane&15), j in [0,192):
    //   j<128: gate g=j>>5, unit u0+(j&31);  j>=128: e col j-128.
    int cols[3];
    float biasv[3];
#pragma unroll
    for (int nt = 0; nt < 3; ++nt) {
        int j = (wave * 3 + nt) * 16 + (lane & 15);
        if (j < 128) {
            int g = j >> 5, u = u0 + (j & 31);
            cols[nt] = g * 512 + u;
            biasv[nt] = (g == 0) ? bi_p[u] : (g == 1) ? bf_p[u] : (g == 2) ? bo_p[u] : bc_p[u];
        } else {
            cols[nt] = 2048 + (j - 128);
            biasv[nt] = be_p[j - 128];
        }
    }
    const int koct = (lane >> 4) * 8;
    bf16x8 B1[3][8], B2[3][16], B1m[8];
#pragma unroll
    for (int nt = 0; nt < 3; ++nt) {
        const ushortT* bw = WslT + cols[nt] * 256;
#pragma unroll
        for (int kt = 0; kt < 8; ++kt)
            B1[nt][kt] = *(const bf16x8*)(bw + kt * 32 + koct);
        const ushortT* bu = UslT + cols[nt] * 512;
#pragma unroll
        for (int kt = 0; kt < 16; ++kt)
            B2[nt][kt] = *(const bf16x8*)(bu + kt * 32 + koct);
    }
    if (wave == 1 || wave == 2) {   // zm = x@Wm: wave w covers cols u0+(w-1)*16..+15
        const ushortT* bm = WslT + (2112 + u0 + (wave - 1) * 16 + (lane & 15)) * 256;
#pragma unroll
        for (int kt = 0; kt < 8; ++kt)
            B1m[kt] = *(const bf16x8*)(bm + kt * 32 + koct);
    }

    const int arow = lane & 3;                 // MFMA A-operand batch row (rows 4-15 dup)
    const bool is_pw = (tid >= 64 && tid < 192);
    const int pb = (tid - 64) >> 5;            // pointwise batch 0..3
    const int pu = (tid - 64) & 31;            // pointwise unit 0..31
    // cooperative tagged-h fetch: wave w owns batch row w; lane reads 8 u32 (32B)
    const int prow = wave;
    const int pcolg = lane * 8;                // u32 offset into row (global)
    const int pcoll = lane * 8;                // ushort offset into hLb row (local)

    __syncthreads();

    for (int t = 0; t < T_SZ; ++t) {
        const int par = t & 1, wpar = (t + 1) & 1;
        const unsigned T16 = ((unsigned)t) << 16;

        // ---- phase A: issue a1f x-fragment loads ----
        i32x4 a1f[8];
        {
            const ushortT* xrow = xb + ((b0 + arow) * T_SZ + t) * D_SZ + koct;
#pragma unroll
            for (int kt = 0; kt < 8; ++kt)
                asm volatile("global_load_dwordx4 %0, %1, off"
                             : "=v"(a1f[kt]) : "v"(xrow + kt * 32) : "memory");
        }

        // ---- phase B: speculative bulk read (mirror) — detection IS the read ----
        const unsigned* msrc = Hmir + (par << 15) + (b0 + prow) * 512 + pcolg;
        const unsigned* hsrc = Hbuf32 + (par << 15) + (b0 + prow) * 512 + pcolg;
        i32x4 g0, g1;
        asm volatile("global_load_dwordx4 %0, %2, off sc0\n\t"
                     "global_load_dwordx4 %1, %2, off offset:16 sc0"
                     : "=v"(g0), "=v"(g1) : "v"(msrc) : "memory");
        // drain stores + a1f; leave ONLY the 2 newest loads (safe counted window)
        asm volatile("s_waitcnt vmcnt(2)"
                     : "+v"(a1f[0]), "+v"(a1f[1]), "+v"(a1f[2]), "+v"(a1f[3]),
                       "+v"(a1f[4]), "+v"(a1f[5]), "+v"(a1f[6]), "+v"(a1f[7])
                     :: "memory");
        __builtin_amdgcn_sched_barrier(0);

        // ---- x-MFMAs hide the bulk-read latency ----
        f32x4 acc0 = {0.f, 0.f, 0.f, 0.f}, acc1 = {0.f, 0.f, 0.f, 0.f};
        f32x4 accE = {0.f, 0.f, 0.f, 0.f}, acc2 = {0.f, 0.f, 0.f, 0.f};
#pragma unroll
        for (int kt = 0; kt < 8; ++kt) {
            bf16x8 a = __builtin_bit_cast(bf16x8, a1f[kt]);
            acc0 = __builtin_amdgcn_mfma_f32_16x16x32_bf16(a, B1[0][kt], acc0, 0, 0, 0);
            acc1 = __builtin_amdgcn_mfma_f32_16x16x32_bf16(a, B1[1][kt], acc1, 0, 0, 0);
            accE = __builtin_amdgcn_mfma_f32_16x16x32_bf16(a, B1[2][kt], accE, 0, 0, 0);
        }
        if (wave == 1 || wave == 2) {
#pragma unroll
            for (int kt = 0; kt < 8; ++kt) {
                bf16x8 a = __builtin_bit_cast(bf16x8, a1f[kt]);
                acc2 = __builtin_amdgcn_mfma_f32_16x16x32_bf16(a, B1m[kt], acc2, 0, 0, 0);
            }
        }

        // ---- validate loop: tags==t? retry alternating LLC/mirror (R15) ----
        {
            unsigned it = 0;
            while (true) {
                asm volatile("s_waitcnt vmcnt(0)"
                             : "+v"(g0), "+v"(g1) :: "memory");
                unsigned d = (((unsigned)g0[0] ^ T16) | ((unsigned)g0[1] ^ T16)) |
                             (((unsigned)g0[2] ^ T16) | ((unsigned)g0[3] ^ T16));
                d |= (((unsigned)g1[0] ^ T16) | ((unsigned)g1[1] ^ T16)) |
                     (((unsigned)g1[2] ^ T16) | ((unsigned)g1[3] ^ T16));
                if (__all((d & 0xFFFF0000u) == 0u)) break;
                if ((it & 1u) == 0u) {   // LLC (authoritative, guarantees progress)
                    asm volatile("global_load_dwordx4 %0, %2, off sc0 sc1\n\t"
                                 "global_load_dwordx4 %1, %2, off offset:16 sc0 sc1"
                                 : "=v"(g0), "=v"(g1) : "v"(hsrc) : "memory");
                } else {                 // mirror (L2-local fast path)
                    asm volatile("global_load_dwordx4 %0, %2, off sc0\n\t"
                                 "global_load_dwordx4 %1, %2, off offset:16 sc0"
                                 : "=v"(g0), "=v"(g1) : "v"(msrc) : "memory");
                }
                ++it;
            }
        }
        __builtin_amdgcn_sched_barrier(0);

        // ---- phase C: strip tags, pack bf16 pairs, stage into LDS ----
        {
            unsigned p0 = ((unsigned)g0[0] & 0xFFFFu) | ((unsigned)g0[1] << 16);
            unsigned p1 = ((unsigned)g0[2] & 0xFFFFu) | ((unsigned)g0[3] << 16);
            unsigned p2 = ((unsigned)g1[0] & 0xFFFFu) | ((unsigned)g1[1] << 16);
            unsigned p3 = ((unsigned)g1[2] & 0xFFFFu) | ((unsigned)g1[3] << 16);
            i32x4 P = {(int)p0, (int)p1, (int)p2, (int)p3};
            *(i32x4*)&hLb[prow][pcoll] = P;
        }
        __syncthreads();   // S1: h tile staged

        // ---- phase D: h-MFMAs from LDS ----
#pragma unroll
        for (int kt = 0; kt < 16; ++kt) {
            bf16x8 a = *(const bf16x8*)&hLb[arow][kt * 32 + koct];
            acc0 = __builtin_amdgcn_mfma_f32_16x16x32_bf16(a, B2[0][kt], acc0, 0, 0, 0);
            acc1 = __builtin_amdgcn_mfma_f32_16x16x32_bf16(a, B2[1][kt], acc1, 0, 0, 0);
            accE = __builtin_amdgcn_mfma_f32_16x16x32_bf16(a, B2[2][kt], accE, 0, 0, 0);
        }

        // ---- phase E: epilogue (C/D: col=lane&15, row=(lane>>4)*4+i; rows 0..3 in lanes<16) ----
        if (lane < 16) {
#pragma unroll
            for (int nt = 0; nt < 3; ++nt) {
                int j = (wave * 3 + nt) * 16 + lane;
                f32x4 a = (nt == 0) ? acc0 : (nt == 1) ? acc1 : accE;
#pragma unroll
                for (int i = 0; i < 4; ++i) {
                    int b = i;   // batch row
                    float z = clip10(a[i] + biasv[nt]);
                    if (j < 128) {
                        g_lds[j >> 5][b][j & 31] = ((j >> 5) == 3) ? tanh_fast(z) : sigm_fast(z);
                    } else {
                        e_lds[b][j - 128] = z;
                    }
                }
            }
            if (wave == 1 || wave == 2) {
#pragma unroll
                for (int i = 0; i < 4; ++i)
                    zm_lds[i][(wave - 1) * 16 + lane] = acc2[i];
            }
        }
        __syncthreads();   // S2: gates/e/zm ready

        // ---- phase F: pointwise + dual tagged-h release (waves 1,2) ----
        if (is_pw) {
            // max-free softmax numerators: thread owns 2 physical slots
            const int base = pu * 2;
            const int k0 = t - 1 - base;
            float wv0 = __expf(e_lds[pb][(unsigned)(k0) & 63]);
            float wv1 = __expf(e_lds[pb][(unsigned)(k0 - 1) & 63]);
            float ssum = wv0 + wv1;
#pragma unroll
            for (int d = 1; d < 32; d <<= 1) ssum += __shfl_xor(ssum, d);
            float2 wq = {wv0, wv1};
            *(float2*)&w_lds[pb][base] = wq;
            asm volatile("" ::: "memory");   // keep ds_write before ds_reads
            float attn = 0.f;
            const float4* wr = (const float4*)&w_lds[pb][0];
            const float4* mr = (const float4*)&memF[pb * MEMF_PB + pu * MEMF_ROW];
#pragma unroll
            for (int p4i = 0; p4i < 16; ++p4i) {
                float4 w4 = wr[p4i], m4 = mr[p4i];
                attn = fmaf(w4.x, m4.x, attn);
                attn = fmaf(w4.y, m4.y, attn);
                attn = fmaf(w4.z, m4.z, attn);
                attn = fmaf(w4.w, m4.w, attn);
            }
            attn /= ssum;
            float ig = g_lds[0][pb][pu];
            float fg = g_lds[1][pb][pu];
            float og = g_lds[2][pb][pu];
            float ct = g_lds[3][pb][pu];
            float c = fg * (attn + zm_lds[pb][pu]) + ig * ct;
            float h = og * tanh_fast(c);
            // dual tagged-h release: mirror (L2) first, then authoritative LLC
            unsigned tagval = (((unsigned)(t + 1)) << 16) | (unsigned)f2b(h);
            const unsigned off = (unsigned)((wpar << 15) + (b0 + pb) * 512 + u0 + pu);
            asm volatile("global_store_dword %0, %1, off sc0"
                         :: "v"(Hmir + off), "v"(tagval) : "memory");
            asm volatile("global_store_dword %0, %1, off sc0 sc1"
                         :: "v"(Hbuf32 + off), "v"(tagval) : "memory");
            // off-critical-path writes (acks drained by next step's vmcnt(2))
            const float* oaddr = out + ((b0 + pb) * T_SZ + t) * U_SZ + u0 + pu;
            asm volatile("global_store_dword %0, %1, off"
                         :: "v"(oaddr), "v"(h) : "memory");
            memF[pb * MEMF_PB + pu * MEMF_ROW + (t & 63)] = c;
        }
        // no end barrier: S1(t+1) separates C(t+1) hLb writes from D(t) reads;
        // F(t) g/e/zm/memF readers precede S1(t+1) which precedes E(t+1) writers.
        // memF/w_lds rows are thread/wave-private respectively.
    }
}

// ---------- launch ----------
extern "C" void kernel_launch(void* const* d_in, const int* in_sizes, int n_in,
                              void* d_out, int out_size, void* d_ws, size_t ws_size,
                              hipStream_t stream) {
    const float* x  = (const float*)d_in[0];
    const float* Wi = (const float*)d_in[1];
    const float* Ui = (const float*)d_in[2];
    const float* bi = (const float*)d_in[3];
    const float* Wf = (const float*)d_in[4];
    const float* Uf = (const float*)d_in[5];
    const float* bf = (const float*)d_in[6];
    const float* Wo = (const float*)d_in[7];
    const float* Uo = (const float*)d_in[8];
    const float* bo = (const float*)d_in[9];
    const float* Wc = (const float*)d_in[10];
    const float* Uc = (const float*)d_in[11];
    const float* bc = (const float*)d_in[12];
    const float* Wm = (const float*)d_in[13];
    const float* We = (const float*)d_in[14];
    const float* Ue = (const float*)d_in[15];
    const float* be = (const float*)d_in[16];

    char* ws = (char*)d_ws;
    const size_t off_xb    = 0;
    const size_t off_uslt  = off_xb + (size_t)B_SZ * T_SZ * D_SZ * 2;   // 16,777,216
    const size_t off_wslt  = off_uslt + (size_t)2112 * 512 * 2;         // +2,162,688
    const size_t off_hbuf  = off_wslt + (size_t)2624 * 256 * 2;         // +1,343,488
    const size_t off_hmir  = off_hbuf + 262144;
    ushortT* xb       = (ushortT*)(ws + off_xb);
    ushortT* UslT     = (ushortT*)(ws + off_uslt);
    ushortT* WslT     = (ushortT*)(ws + off_wslt);
    unsigned* Hbuf32  = (unsigned*)(ws + off_hbuf);   // 2*64*512*4 = 262,144 B
    unsigned* Hmir    = (unsigned*)(ws + off_hmir);   // 262,144 B
    float* out = (float*)d_out;

    // zero both tagged-h double buffers (tags -> 0) — re-zeroed every replay
    (void)hipMemsetAsync(ws + off_hbuf, 0, 524288, stream);

    prep_xb_k<<<2048, 256, 0, stream>>>(x, xb);
    prep_uw_k<<<2048, 256, 0, stream>>>(Ui, Uf, Uo, Uc, Ue, Wi, Wf, Wo, Wc, We, Wm,
                                        UslT, WslT);

    xlstm_rec<<<dim3(256), dim3(256), 0, stream>>>(
        xb, UslT, WslT, bi, bf, bo, bc, be, Hbuf32, Hmir, out);
}

// Round 20
// 1663.950 us; speedup vs baseline: 1.1775x; 1.1775x over previous
//
#include <hip/hip_runtime.h>
#include <hip/hip_bf16.h>

typedef unsigned short ushortT;
typedef __attribute__((ext_vector_type(8))) short bf16x8;
typedef __attribute__((ext_vector_type(4))) float f32x4;
typedef __attribute__((ext_vector_type(4))) int i32x4;

#define B_SZ 64
#define T_SZ 512
#define D_SZ 256
#define U_SZ 512
#define M_SZ 64

// ---------- helpers ----------
__device__ __forceinline__ ushortT f2b(float f) {
    __hip_bfloat16 h = __float2bfloat16(f);
    union { __hip_bfloat16 h; ushortT u; } c; c.h = h; return c.u;
}
__device__ __forceinline__ float clip10(float v) {
    return fminf(fmaxf(v, -10.f), 10.f);
}
__device__ __forceinline__ float tanh_fast(float z) {
    float e = __expf(2.f * z);
    return 1.f - 2.f / (e + 1.f);   // inf-safe
}
__device__ __forceinline__ float sigm_fast(float z) {
    return 1.f / (1.f + __expf(-z));
}

// ---------- prep: x -> clipped bf16 ----------
__global__ void prep_xb_k(const float* __restrict__ x, ushortT* __restrict__ xb) {
    const int n4 = (B_SZ * T_SZ * D_SZ) / 4;
    for (int i = blockIdx.x * blockDim.x + threadIdx.x; i < n4; i += gridDim.x * blockDim.x) {
        float4 v = ((const float4*)x)[i];
        ushort4 o;
        o.x = f2b(clip10(v.x));
        o.y = f2b(clip10(v.y));
        o.z = f2b(clip10(v.z));
        o.w = f2b(clip10(v.w));
        ((ushort4*)xb)[i] = o;
    }
}

// ---------- prep: U^T and W^T bf16 (transposed, col-major rows) ----------
// UslT cols: 0..2047 gate U cols, 2048..2111 Ue cols.
// WslT cols: 0..2047 gate W cols, 2048..2111 We cols, 2112..2623 Wm cols.
__global__ void prep_uw_k(const float* __restrict__ Ui, const float* __restrict__ Uf,
                          const float* __restrict__ Uo, const float* __restrict__ Uc,
                          const float* __restrict__ Ue,
                          const float* __restrict__ Wi, const float* __restrict__ Wf,
                          const float* __restrict__ Wo, const float* __restrict__ Wc,
                          const float* __restrict__ We, const float* __restrict__ Wm,
                          ushortT* __restrict__ UslT, ushortT* __restrict__ WslT) {
    const int NU = 2112 * 512;
    const int NW = 2624 * 256;
    for (int i = blockIdx.x * blockDim.x + threadIdx.x; i < NU + NW; i += gridDim.x * blockDim.x) {
        if (i < NU) {
            int c = i >> 9, k = i & 511;
            float v;
            if (c < 2048) {
                int g = c >> 9, u = c & 511;
                const float* U = (g == 0) ? Ui : (g == 1) ? Uf : (g == 2) ? Uo : Uc;
                v = U[k * 512 + u];
            } else {
                v = Ue[k * 64 + (c - 2048)];
            }
            UslT[i] = f2b(v);
        } else {
            int j = i - NU;
            int c = j >> 8, k = j & 255;
            float v;
            if (c < 2048) {
                int g = c >> 9, u = c & 511;
                const float* W = (g == 0) ? Wi : (g == 1) ? Wf : (g == 2) ? Wo : Wc;
                v = W[k * 512 + u];
            } else if (c < 2112) {
                v = We[k * 64 + (c - 2048)];
            } else {
                v = Wm[k * 512 + (c - 2112)];
            }
            WslT[j] = f2b(v);
        }
    }
}

#define MEMF_PB 1096   // floats per batch block (16 rows x 68 + 8 skew)
#define MEMF_ROW 68

// ---------- persistent recurrent kernel ----------
// FINAL = R15 (measured optimum 1649us). Tagged self-validating h exchange
// (tag<<16 | bf16) with dual-path stores (L2 mirror sc0 + authoritative LLC
// sc0 sc1); detection merged into the speculative bulk read; retries alternate
// LLC/mirror (measured optimal vs mirror-biased and LLC-only). Cooperative
// receive (1 line/lane). 2 barriers/step. Placement-independent (G16): the
// LLC copy alone guarantees progress; the mirror is advisory fast-path.
__global__ __launch_bounds__(256, 1) void xlstm_rec(
    const ushortT* __restrict__ xb,    // [B*T][256] bf16 (clipped)
    const ushortT* __restrict__ UslT,  // [2112][512] bf16
    const ushortT* __restrict__ WslT,  // [2624][256] bf16
    const float* __restrict__ bi_p, const float* __restrict__ bf_p,
    const float* __restrict__ bo_p, const float* __restrict__ bc_p,
    const float* __restrict__ be_p,
    unsigned* __restrict__ Hbuf32,     // [2][64][512] u32 tagged h (LLC copy)
    unsigned* __restrict__ Hmir,       // [2][64][512] u32 tagged h (L2 mirror)
    float* __restrict__ out)           // [64][512][512] fp32
{
    const int bid = blockIdx.x, tid = threadIdx.x;
    const int grp = bid & 7, rank = bid >> 3;
    const int wave = tid >> 6, lane = tid & 63;
    const int b0 = grp << 3;     // batch base
    const int u0 = rank << 4;    // unit base

    __shared__ float memF[8 * MEMF_PB];     // c ring: [pb][pu][slot(64)+pad] (thread-private rows)
    __shared__ float g_lds[4][8][16];       // i,f,o,ctilde
    __shared__ float e_lds[8][68];          // raw clipped e-logits (logical idx)
    __shared__ float w_lds[8][72];          // softmax numerators (physical slot)
    __shared__ float zm_lds[8][16];         // x_t @ Wm slice
    __shared__ ushortT hLb[8][520];         // h tile bf16, padded stride (1040B)

    for (int i = tid; i < 8 * MEMF_PB; i += 256) memF[i] = 0.f;

    // ---- register-resident weight B-fragments ----
    int cols[2];
    float biasv[2];
#pragma unroll
    for (int nt = 0; nt < 2; ++nt) {
        int j = wave * 32 + nt * 16 + (lane & 15);
        if (j < 64) {
            int g = j >> 4, u = u0 + (j & 15);
            cols[nt] = g * 512 + u;
            biasv[nt] = (g == 0) ? bi_p[u] : (g == 1) ? bf_p[u] : (g == 2) ? bo_p[u] : bc_p[u];
        } else {
            cols[nt] = 2048 + (j - 64);
            biasv[nt] = be_p[j - 64];
        }
    }
    const int koct = (lane >> 4) * 8;
    bf16x8 B1[2][8], B2[2][16], B1m[8];
#pragma unroll
    for (int nt = 0; nt < 2; ++nt) {
        const ushortT* bw = WslT + cols[nt] * 256;
#pragma unroll
        for (int kt = 0; kt < 8; ++kt)
            B1[nt][kt] = *(const bf16x8*)(bw + kt * 32 + koct);
        const ushortT* bu = UslT + cols[nt] * 512;
#pragma unroll
        for (int kt = 0; kt < 16; ++kt)
            B2[nt][kt] = *(const bf16x8*)(bu + kt * 32 + koct);
    }
    if (wave == 1) {   // Wm fragment (zm = x@Wm via MFMA)
        const ushortT* bm = WslT + (2112 + u0 + (lane & 15)) * 256;
#pragma unroll
        for (int kt = 0; kt < 8; ++kt)
            B1m[kt] = *(const bf16x8*)(bm + kt * 32 + koct);
    }

    const int arow = lane & 7;                 // MFMA A-operand batch row
    const bool is_pw = (tid >= 64 && tid < 192);
    const int pb = (tid - 64) >> 4;
    const int pu = (tid - 64) & 15;
    // bulk tagged-h fetch: wave w owns rows 2w (lanes<32), 2w+1 (lanes>=32)
    const int prow = 2 * wave + (lane >> 5);
    const int pcol = (lane & 31) * 16;         // 16 u32 units per lane (one 64B line)

    __syncthreads();

    for (int t = 0; t < T_SZ; ++t) {
        const int par = t & 1, wpar = (t + 1) & 1;
        const unsigned T16 = ((unsigned)t) << 16;

        // ---- phase A: issue a1f x-fragment loads ----
        i32x4 a1f[8];
        {
            const ushortT* xrow = xb + ((b0 + arow) * T_SZ + t) * D_SZ + koct;
#pragma unroll
            for (int kt = 0; kt < 8; ++kt)
                asm volatile("global_load_dwordx4 %0, %1, off"
                             : "=v"(a1f[kt]) : "v"(xrow + kt * 32) : "memory");
        }

        // ---- phase B: speculative bulk read (mirror) — detection IS the read ----
        const unsigned* msrc = Hmir + (par << 15) + (b0 + prow) * 512 + pcol;
        const unsigned* hsrc = Hbuf32 + (par << 15) + (b0 + prow) * 512 + pcol;
        i32x4 g0, g1, g2, g3;
        asm volatile("global_load_dwordx4 %0, %4, off sc0\n\t"
                     "global_load_dwordx4 %1, %4, off offset:16 sc0\n\t"
                     "global_load_dwordx4 %2, %4, off offset:32 sc0\n\t"
                     "global_load_dwordx4 %3, %4, off offset:48 sc0"
                     : "=v"(g0), "=v"(g1), "=v"(g2), "=v"(g3)
                     : "v"(msrc) : "memory");
        // wait until only the 4 bulk loads remain -> a1f + older F stores done
        asm volatile("s_waitcnt vmcnt(4)"
                     : "+v"(a1f[0]), "+v"(a1f[1]), "+v"(a1f[2]), "+v"(a1f[3]),
                       "+v"(a1f[4]), "+v"(a1f[5]), "+v"(a1f[6]), "+v"(a1f[7])
                     :: "memory");
        __builtin_amdgcn_sched_barrier(0);

        // ---- x-MFMAs hide the bulk-read latency ----
        f32x4 acc0 = {0.f, 0.f, 0.f, 0.f}, acc1 = {0.f, 0.f, 0.f, 0.f};
        f32x4 acc2 = {0.f, 0.f, 0.f, 0.f};
#pragma unroll
        for (int kt = 0; kt < 8; ++kt) {
            bf16x8 a = __builtin_bit_cast(bf16x8, a1f[kt]);
            acc0 = __builtin_amdgcn_mfma_f32_16x16x32_bf16(a, B1[0][kt], acc0, 0, 0, 0);
            acc1 = __builtin_amdgcn_mfma_f32_16x16x32_bf16(a, B1[1][kt], acc1, 0, 0, 0);
        }
        if (wave == 1) {
#pragma unroll
            for (int kt = 0; kt < 8; ++kt) {
                bf16x8 a = __builtin_bit_cast(bf16x8, a1f[kt]);
                acc2 = __builtin_amdgcn_mfma_f32_16x16x32_bf16(a, B1m[kt], acc2, 0, 0, 0);
            }
        }

        // ---- validate loop: tags==t? retry alternating LLC/mirror ----
        {
            unsigned it = 0;
            while (true) {
                asm volatile("s_waitcnt vmcnt(0)"
                             : "+v"(g0), "+v"(g1), "+v"(g2), "+v"(g3) :: "memory");
                unsigned d = (((unsigned)g0[0] ^ T16) | ((unsigned)g0[1] ^ T16)) |
                             (((unsigned)g0[2] ^ T16) | ((unsigned)g0[3] ^ T16));
                d |= (((unsigned)g1[0] ^ T16) | ((unsigned)g1[1] ^ T16)) |
                     (((unsigned)g1[2] ^ T16) | ((unsigned)g1[3] ^ T16));
                d |= (((unsigned)g2[0] ^ T16) | ((unsigned)g2[1] ^ T16)) |
                     (((unsigned)g2[2] ^ T16) | ((unsigned)g2[3] ^ T16));
                d |= (((unsigned)g3[0] ^ T16) | ((unsigned)g3[1] ^ T16)) |
                     (((unsigned)g3[2] ^ T16) | ((unsigned)g3[3] ^ T16));
                if (__all((d & 0xFFFF0000u) == 0u)) break;
                if ((it & 1u) == 0u) {   // LLC (authoritative, guarantees progress)
                    asm volatile("global_load_dwordx4 %0, %4, off sc0 sc1\n\t"
                                 "global_load_dwordx4 %1, %4, off offset:16 sc0 sc1\n\t"
                                 "global_load_dwordx4 %2, %4, off offset:32 sc0 sc1\n\t"
                                 "global_load_dwordx4 %3, %4, off offset:48 sc0 sc1"
                                 : "=v"(g0), "=v"(g1), "=v"(g2), "=v"(g3)
                                 : "v"(hsrc) : "memory");
                } else {                 // mirror (L2-local fast path)
                    asm volatile("global_load_dwordx4 %0, %4, off sc0\n\t"
                                 "global_load_dwordx4 %1, %4, off offset:16 sc0\n\t"
                                 "global_load_dwordx4 %2, %4, off offset:32 sc0\n\t"
                                 "global_load_dwordx4 %3, %4, off offset:48 sc0"
                                 : "=v"(g0), "=v"(g1), "=v"(g2), "=v"(g3)
                                 : "v"(msrc) : "memory");
                }
                ++it;
            }
        }
        __builtin_amdgcn_sched_barrier(0);

        // ---- phase C: strip tags, pack bf16 pairs, stage into LDS ----
        {
            unsigned p0 = ((unsigned)g0[0] & 0xFFFFu) | ((unsigned)g0[1] << 16);
            unsigned p1 = ((unsigned)g0[2] & 0xFFFFu) | ((unsigned)g0[3] << 16);
            unsigned p2 = ((unsigned)g1[0] & 0xFFFFu) | ((unsigned)g1[1] << 16);
            unsigned p3 = ((unsigned)g1[2] & 0xFFFFu) | ((unsigned)g1[3] << 16);
            unsigned p4 = ((unsigned)g2[0] & 0xFFFFu) | ((unsigned)g2[1] << 16);
            unsigned p5 = ((unsigned)g2[2] & 0xFFFFu) | ((unsigned)g2[3] << 16);
            unsigned p6 = ((unsigned)g3[0] & 0xFFFFu) | ((unsigned)g3[1] << 16);
            unsigned p7 = ((unsigned)g3[2] & 0xFFFFu) | ((unsigned)g3[3] << 16);
            i32x4 P0 = {(int)p0, (int)p1, (int)p2, (int)p3};
            i32x4 P1 = {(int)p4, (int)p5, (int)p6, (int)p7};
            *(i32x4*)&hLb[prow][pcol] = P0;
            *(i32x4*)&hLb[prow][pcol + 8] = P1;
        }
        __syncthreads();   // S1: h tile staged

        // ---- phase D: h-MFMAs from LDS ----
#pragma unroll
        for (int kt = 0; kt < 16; ++kt) {
            bf16x8 a = *(const bf16x8*)&hLb[arow][kt * 32 + koct];
            acc0 = __builtin_amdgcn_mfma_f32_16x16x32_bf16(a, B2[0][kt], acc0, 0, 0, 0);
            acc1 = __builtin_amdgcn_mfma_f32_16x16x32_bf16(a, B2[1][kt], acc1, 0, 0, 0);
        }

        // ---- phase E: epilogue (C/D: col=lane&15, row=(lane>>4)*4+i; rows 0..7 in lanes<32) ----
        if (lane < 32) {
#pragma unroll
            for (int nt = 0; nt < 2; ++nt) {
                int j = wave * 32 + nt * 16 + (lane & 15);
                f32x4 a = nt ? acc1 : acc0;
#pragma unroll
                for (int i = 0; i < 4; ++i) {
                    int b = ((lane >> 4) << 2) + i;
                    float z = clip10(a[i] + biasv[nt]);
                    if (j < 64) {
                        int g = j >> 4;
                        g_lds[g][b][j & 15] = (g == 3) ? tanh_fast(z) : sigm_fast(z);
                    } else {
                        e_lds[b][j - 64] = z;
                    }
                }
            }
            if (wave == 1) {
#pragma unroll
                for (int i = 0; i < 4; ++i)
                    zm_lds[((lane >> 4) << 2) + i][lane & 15] = acc2[i];
            }
        }
        __syncthreads();   // S2: gates/e/zm ready

        // ---- phase F: pointwise + dual tagged-h release (waves 1,2) ----
        if (is_pw) {
            // max-free softmax numerators (|e|<=10 -> exp safe in fp32)
            const int base = pu * 4;
            const int k0 = t - 1 - base;
            float wv0 = __expf(e_lds[pb][(unsigned)(k0) & 63]);
            float wv1 = __expf(e_lds[pb][(unsigned)(k0 - 1) & 63]);
            float wv2 = __expf(e_lds[pb][(unsigned)(k0 - 2) & 63]);
            float wv3 = __expf(e_lds[pb][(unsigned)(k0 - 3) & 63]);
            float ssum = (wv0 + wv1) + (wv2 + wv3);
#pragma unroll
            for (int d = 1; d < 16; d <<= 1) ssum += __shfl_xor(ssum, d);
            float4 wq = {wv0, wv1, wv2, wv3};
            *(float4*)&w_lds[pb][base] = wq;
            asm volatile("" ::: "memory");   // keep ds_write before ds_reads
            float attn = 0.f;
            const float4* wr = (const float4*)&w_lds[pb][0];
            const float4* mr = (const float4*)&memF[pb * MEMF_PB + pu * MEMF_ROW];
#pragma unroll
            for (int p4i = 0; p4i < 16; ++p4i) {
                float4 w4 = wr[p4i], m4 = mr[p4i];
                attn = fmaf(w4.x, m4.x, attn);
                attn = fmaf(w4.y, m4.y, attn);
                attn = fmaf(w4.z, m4.z, attn);
                attn = fmaf(w4.w, m4.w, attn);
            }
            attn /= ssum;
            float ig = g_lds[0][pb][pu];
            float fg = g_lds[1][pb][pu];
            float og = g_lds[2][pb][pu];
            float ct = g_lds[3][pb][pu];
            float c = fg * (attn + zm_lds[pb][pu]) + ig * ct;
            float h = og * tanh_fast(c);
            // dual tagged-h release: mirror (L2) first, then authoritative LLC
            unsigned tagval = (((unsigned)(t + 1)) << 16) | (unsigned)f2b(h);
            const unsigned off = (unsigned)((wpar << 15) + (b0 + pb) * 512 + u0 + pu);
            asm volatile("global_store_dword %0, %1, off sc0"
                         :: "v"(Hmir + off), "v"(tagval) : "memory");
            asm volatile("global_store_dword %0, %1, off sc0 sc1"
                         :: "v"(Hbuf32 + off), "v"(tagval) : "memory");
            // off-critical-path writes (acks drained by next step's vmcnt(4))
            const float* oaddr = out + ((b0 + pb) * T_SZ + t) * U_SZ + u0 + pu;
            asm volatile("global_store_dword %0, %1, off"
                         :: "v"(oaddr), "v"(h) : "memory");
            memF[pb * MEMF_PB + pu * MEMF_ROW + (t & 63)] = c;
        }
        // no end barrier: S1(t+1) separates C(t+1) hLb writes from D(t) reads;
        // F(t) g/e/zm readers precede S1(t+1) which precedes E(t+1) writers.
        // memF/w_lds rows are wave-private.
    }
}

// ---------- launch ----------
extern "C" void kernel_launch(void* const* d_in, const int* in_sizes, int n_in,
                              void* d_out, int out_size, void* d_ws, size_t ws_size,
                              hipStream_t stream) {
    const float* x  = (const float*)d_in[0];
    const float* Wi = (const float*)d_in[1];
    const float* Ui = (const float*)d_in[2];
    const float* bi = (const float*)d_in[3];
    const float* Wf = (const float*)d_in[4];
    const float* Uf = (const float*)d_in[5];
    const float* bf = (const float*)d_in[6];
    const float* Wo = (const float*)d_in[7];
    const float* Uo = (const float*)d_in[8];
    const float* bo = (const float*)d_in[9];
    const float* Wc = (const float*)d_in[10];
    const float* Uc = (const float*)d_in[11];
    const float* bc = (const float*)d_in[12];
    const float* Wm = (const float*)d_in[13];
    const float* We = (const float*)d_in[14];
    const float* Ue = (const float*)d_in[15];
    const float* be = (const float*)d_in[16];

    char* ws = (char*)d_ws;
    const size_t off_xb    = 0;
    const size_t off_uslt  = off_xb + (size_t)B_SZ * T_SZ * D_SZ * 2;   // 16,777,216
    const size_t off_wslt  = off_uslt + (size_t)2112 * 512 * 2;         // +2,162,688
    const size_t off_hbuf  = off_wslt + (size_t)2624 * 256 * 2;         // +1,343,488
    const size_t off_hmir  = off_hbuf + 262144;
    ushortT* xb       = (ushortT*)(ws + off_xb);
    ushortT* UslT     = (ushortT*)(ws + off_uslt);
    ushortT* WslT     = (ushortT*)(ws + off_wslt);
    unsigned* Hbuf32  = (unsigned*)(ws + off_hbuf);   // 2*64*512*4 = 262,144 B
    unsigned* Hmir    = (unsigned*)(ws + off_hmir);   // 262,144 B
    float* out = (float*)d_out;

    // zero both tagged-h double buffers (tags -> 0) — re-zeroed every replay
    (void)hipMemsetAsync(ws + off_hbuf, 0, 524288, stream);

    prep_xb_k<<<2048, 256, 0, stream>>>(x, xb);
    prep_uw_k<<<2048, 256, 0, stream>>>(Ui, Uf, Uo, Uc, Ue, Wi, Wf, Wo, Wc, We, Wm,
                                        UslT, WslT);

    xlstm_rec<<<dim3(256), dim3(256), 0, stream>>>(
        xb, UslT, WslT, bi, bf, bo, bc, be, Hbuf32, Hmir, out);
}